// Round 1
// baseline (982.345 us; speedup 1.0000x reference)
//
#include <hip/hip_runtime.h>
#include <math.h>

#define KNN 20
#define PPTS 1024
#define NCL 16

__device__ __forceinline__ float lrelu(float x) { return x > 0.f ? x : 0.2f * x; }

// ---------------- gather: h0[b*P+p, :] = features[clusters[b*P+p], :] ----------------
__global__ void gather_kernel(const float4* __restrict__ feat,
                              const int* __restrict__ clusters,
                              float4* __restrict__ h0) {
    int n = blockIdx.x * 256 + threadIdx.x;   // over NCL*PPTS*32 float4s
    int c4 = n & 31;
    int row = n >> 5;
    int src = clusters[row];
    h0[(size_t)row * 32 + c4] = feat[(size_t)src * 32 + c4];
}

// ---------------- squared row norms ----------------
__global__ void sq_kernel(const float* __restrict__ h, int ldh, int C,
                          float* __restrict__ sq) {
    int lane = threadIdx.x & 63;
    int wid  = threadIdx.x >> 6;
    int row  = blockIdx.x * 4 + wid;
    const float* hr = h + (size_t)row * ldh;
    float s = 0.f;
    for (int c = lane; c < C; c += 64) { float v = hr[c]; s += v * v; }
    #pragma unroll
    for (int off = 32; off; off >>= 1) s += __shfl_down(s, off);
    if (lane == 0) sq[row] = s;
}

// ---------------- gram: pd[b][i][j] = 2*h_i.h_j - sq_i - sq_j ----------------
__global__ __launch_bounds__(256) void gram_kernel(
    const float* __restrict__ h, int ldh, int C,
    const float* __restrict__ sq, float* __restrict__ pd)
{
    __shared__ float As[16][68];
    __shared__ float Bs[16][68];
    const int b = blockIdx.z;
    const float* hb = h + (size_t)b * PPTS * ldh;
    const float* sqb = sq + b * PPTS;
    float* pdb = pd + (size_t)b * PPTS * PPTS;
    const int i0 = blockIdx.y * 64, j0 = blockIdx.x * 64;
    const int t = threadIdx.x;
    const int lr = t >> 2;
    const int lc = (t & 3) * 4;
    const int tx = t & 15, ty = t >> 4;
    float acc[4][4];
    #pragma unroll
    for (int u = 0; u < 4; u++)
        #pragma unroll
        for (int v = 0; v < 4; v++) acc[u][v] = 0.f;

    for (int kk = 0; kk < C; kk += 16) {
        float4 a  = *(const float4*)&hb[(size_t)(i0 + lr) * ldh + kk + lc];
        float4 bb = *(const float4*)&hb[(size_t)(j0 + lr) * ldh + kk + lc];
        __syncthreads();
        As[lc+0][lr] = a.x;  As[lc+1][lr] = a.y;  As[lc+2][lr] = a.z;  As[lc+3][lr] = a.w;
        Bs[lc+0][lr] = bb.x; Bs[lc+1][lr] = bb.y; Bs[lc+2][lr] = bb.z; Bs[lc+3][lr] = bb.w;
        __syncthreads();
        #pragma unroll
        for (int k = 0; k < 16; k++) {
            float4 ar = *(const float4*)&As[k][ty * 4];
            float4 br = *(const float4*)&Bs[k][tx * 4];
            float av[4] = {ar.x, ar.y, ar.z, ar.w};
            float bv[4] = {br.x, br.y, br.z, br.w};
            #pragma unroll
            for (int u = 0; u < 4; u++)
                #pragma unroll
                for (int v = 0; v < 4; v++)
                    acc[u][v] = fmaf(av[u], bv[v], acc[u][v]);
        }
    }
    float sqi[4], sqj[4];
    #pragma unroll
    for (int u = 0; u < 4; u++) sqi[u] = sqb[i0 + ty * 4 + u];
    #pragma unroll
    for (int v = 0; v < 4; v++) sqj[v] = sqb[j0 + tx * 4 + v];
    #pragma unroll
    for (int u = 0; u < 4; u++) {
        float4 o;
        o.x = 2.f * acc[u][0] - sqi[u] - sqj[0];
        o.y = 2.f * acc[u][1] - sqi[u] - sqj[1];
        o.z = 2.f * acc[u][2] - sqi[u] - sqj[2];
        o.w = 2.f * acc[u][3] - sqi[u] - sqj[3];
        *(float4*)&pdb[(size_t)(i0 + ty * 4 + u) * PPTS + j0 + tx * 4] = o;
    }
}

// ---------------- top-K (largest pd) per row, wave per row ----------------
__global__ void topk_kernel(const float* __restrict__ pd, int* __restrict__ idx) {
    int lane = threadIdx.x & 63;
    int w = threadIdx.x >> 6;
    int b = blockIdx.y;
    int p = blockIdx.x * 4 + w;
    const float* row = pd + ((size_t)b * PPTS + p) * PPTS;
    float v[16];
    #pragma unroll
    for (int s = 0; s < 16; s++) v[s] = row[s * 64 + lane];
    int* out = idx + ((size_t)b * PPTS + p) * KNN;
    for (int kk = 0; kk < KNN; kk++) {
        float bv = v[0]; int bs = 0;
        #pragma unroll
        for (int s = 1; s < 16; s++) if (v[s] > bv) { bv = v[s]; bs = s; }
        int bj = bs * 64 + lane;
        #pragma unroll
        for (int off = 32; off; off >>= 1) {
            float ov = __shfl_down(bv, off);
            int oj = __shfl_down(bj, off);
            if (ov > bv || (ov == bv && oj < bj)) { bv = ov; bj = oj; }
        }
        bj = __shfl(bj, 0);
        if (lane == 0) out[kk] = bj;
        if ((bj & 63) == lane) v[bj >> 6] = -INFINITY;
    }
}

// ---------------- U/V GEMM: U = H*Wn^T, V = H*(Wc-Wn)^T ----------------
__global__ __launch_bounds__(256) void uv_kernel(
    const float* __restrict__ h, int ldh, int C, int O,
    const float* __restrict__ W,
    float* __restrict__ U, float* __restrict__ V)
{
    __shared__ float As[16][68];
    __shared__ float Bu[16][68];
    __shared__ float Bv[16][68];
    const int r0 = blockIdx.y * 64;
    const int o0 = blockIdx.x * 64;
    const int t = threadIdx.x;
    const int lr = t >> 2;
    const int lc = (t & 3) * 4;
    const int tx = t & 15, ty = t >> 4;
    const int twoC = 2 * C;
    float au[4][4], av[4][4];
    #pragma unroll
    for (int u = 0; u < 4; u++)
        #pragma unroll
        for (int v = 0; v < 4; v++) { au[u][v] = 0.f; av[u][v] = 0.f; }

    for (int kk = 0; kk < C; kk += 16) {
        float4 a  = *(const float4*)&h[(size_t)(r0 + lr) * ldh + kk + lc];
        float4 w1 = *(const float4*)&W[(size_t)(o0 + lr) * twoC + kk + lc];
        float4 w2 = *(const float4*)&W[(size_t)(o0 + lr) * twoC + C + kk + lc];
        __syncthreads();
        As[lc+0][lr] = a.x;  As[lc+1][lr] = a.y;  As[lc+2][lr] = a.z;  As[lc+3][lr] = a.w;
        Bu[lc+0][lr] = w1.x; Bu[lc+1][lr] = w1.y; Bu[lc+2][lr] = w1.z; Bu[lc+3][lr] = w1.w;
        Bv[lc+0][lr] = w2.x - w1.x; Bv[lc+1][lr] = w2.y - w1.y;
        Bv[lc+2][lr] = w2.z - w1.z; Bv[lc+3][lr] = w2.w - w1.w;
        __syncthreads();
        #pragma unroll
        for (int k = 0; k < 16; k++) {
            float4 ar = *(const float4*)&As[k][ty * 4];
            float4 bu = *(const float4*)&Bu[k][tx * 4];
            float4 bw = *(const float4*)&Bv[k][tx * 4];
            float arr[4] = {ar.x, ar.y, ar.z, ar.w};
            float buu[4] = {bu.x, bu.y, bu.z, bu.w};
            float bvv[4] = {bw.x, bw.y, bw.z, bw.w};
            #pragma unroll
            for (int u = 0; u < 4; u++)
                #pragma unroll
                for (int v = 0; v < 4; v++) {
                    au[u][v] = fmaf(arr[u], buu[v], au[u][v]);
                    av[u][v] = fmaf(arr[u], bvv[v], av[u][v]);
                }
        }
    }
    #pragma unroll
    for (int u = 0; u < 4; u++) {
        float4 ou = make_float4(au[u][0], au[u][1], au[u][2], au[u][3]);
        float4 ov = make_float4(av[u][0], av[u][1], av[u][2], av[u][3]);
        size_t base = (size_t)(r0 + ty * 4 + u) * O + o0 + tx * 4;
        *(float4*)&U[base] = ou;
        *(float4*)&V[base] = ov;
    }
}

// ---------------- aggregate: x[p,o] = lrelu(s*(max_k U[idx,o] + V[p,o]) + b) ----------------
__global__ void agg_kernel(const float* __restrict__ U, const float* __restrict__ V,
                           const int* __restrict__ idx, int lgO,
                           const float* __restrict__ sc, const float* __restrict__ bi,
                           float* __restrict__ xout) {
    int n = blockIdx.x * 256 + threadIdx.x;
    int O = 1 << lgO;
    int o = n & (O - 1);
    int pr = n >> lgO;           // b*P+p
    int b = pr >> 10;
    const int* id = idx + (size_t)pr * KNN;
    float m = -INFINITY;
    #pragma unroll
    for (int k = 0; k < KNN; k++) {
        int j = id[k];
        float u = U[((size_t)(b * PPTS + j) << lgO) + o];
        m = fmaxf(m, u);
    }
    float val = (m + V[((size_t)pr << lgO) + o]) * sc[o] + bi[o];
    xout[(size_t)pr * 512 + o] = lrelu(val);
}

// ---------------- conv5: y5 = lrelu(s5*(xc @ W5^T) + b5) ----------------
__global__ __launch_bounds__(256) void conv5_kernel(
    const float* __restrict__ xc, const float* __restrict__ W5,
    const float* __restrict__ s5, const float* __restrict__ b5,
    float* __restrict__ y5)
{
    __shared__ float As[16][68];
    __shared__ float Bs[16][68];
    const int r0 = blockIdx.y * 64;
    const int o0 = blockIdx.x * 64;
    const int t = threadIdx.x;
    const int lr = t >> 2;
    const int lc = (t & 3) * 4;
    const int tx = t & 15, ty = t >> 4;
    float acc[4][4];
    #pragma unroll
    for (int u = 0; u < 4; u++)
        #pragma unroll
        for (int v = 0; v < 4; v++) acc[u][v] = 0.f;

    for (int kk = 0; kk < 512; kk += 16) {
        float4 a  = *(const float4*)&xc[(size_t)(r0 + lr) * 512 + kk + lc];
        float4 bb = *(const float4*)&W5[(size_t)(o0 + lr) * 512 + kk + lc];
        __syncthreads();
        As[lc+0][lr] = a.x;  As[lc+1][lr] = a.y;  As[lc+2][lr] = a.z;  As[lc+3][lr] = a.w;
        Bs[lc+0][lr] = bb.x; Bs[lc+1][lr] = bb.y; Bs[lc+2][lr] = bb.z; Bs[lc+3][lr] = bb.w;
        __syncthreads();
        #pragma unroll
        for (int k = 0; k < 16; k++) {
            float4 ar = *(const float4*)&As[k][ty * 4];
            float4 br = *(const float4*)&Bs[k][tx * 4];
            float av[4] = {ar.x, ar.y, ar.z, ar.w};
            float bv[4] = {br.x, br.y, br.z, br.w};
            #pragma unroll
            for (int u = 0; u < 4; u++)
                #pragma unroll
                for (int v = 0; v < 4; v++)
                    acc[u][v] = fmaf(av[u], bv[v], acc[u][v]);
        }
    }
    #pragma unroll
    for (int u = 0; u < 4; u++) {
        float4 o;
        int oc = o0 + tx * 4;
        o.x = lrelu(acc[u][0] * s5[oc+0] + b5[oc+0]);
        o.y = lrelu(acc[u][1] * s5[oc+1] + b5[oc+1]);
        o.z = lrelu(acc[u][2] * s5[oc+2] + b5[oc+2]);
        o.w = lrelu(acc[u][3] * s5[oc+3] + b5[oc+3]);
        *(float4*)&y5[(size_t)(r0 + ty * 4 + u) * 512 + oc] = o;
    }
}

// ---------------- pool: feat[b] = [max_p y5, mean_p y5] ----------------
__global__ void pool_kernel(const float* __restrict__ y5, float* __restrict__ feat) {
    __shared__ float smax[256], ssum[256];
    int t = threadIdx.x;
    int ol = t & 63, st = t >> 6;
    int b = blockIdx.y;
    int o = blockIdx.x * 64 + ol;
    float m = -INFINITY, s = 0.f;
    for (int p = st; p < PPTS; p += 4) {
        float v = y5[((size_t)b * PPTS + p) * 512 + o];
        m = fmaxf(m, v); s += v;
    }
    smax[t] = m; ssum[t] = s;
    __syncthreads();
    if (st == 0) {
        #pragma unroll
        for (int q = 1; q < 4; q++) { m = fmaxf(m, smax[q * 64 + ol]); s += ssum[q * 64 + ol]; }
        feat[(size_t)b * 1024 + o] = m;
        feat[(size_t)b * 1024 + 512 + o] = s * (1.f / 1024.f);
    }
}

// ---------------- final MLP ----------------
__global__ void mlp1_kernel(const float* __restrict__ feat, const float* __restrict__ L1,
                            const float* __restrict__ s6, const float* __restrict__ b6,
                            float* __restrict__ z1) {
    int n = blockIdx.x * 256 + threadIdx.x;   // 16*512
    int o = n & 511, b = n >> 9;
    const float* f = feat + (size_t)b * 1024;
    const float* w = L1 + (size_t)o * 1024;
    float acc = 0.f;
    for (int c = 0; c < 1024; c++) acc = fmaf(f[c], w[c], acc);
    z1[n] = lrelu(acc * s6[o] + b6[o]);
}

__global__ void mlp2_kernel(const float* __restrict__ z1, const float* __restrict__ L2,
                            const float* __restrict__ bl2,
                            const float* __restrict__ s7, const float* __restrict__ b7,
                            float* __restrict__ z2) {
    int n = blockIdx.x * 256 + threadIdx.x;   // 16*256
    int o = n & 255, b = n >> 8;
    const float* f = z1 + (size_t)b * 512;
    const float* w = L2 + (size_t)o * 512;
    float acc = 0.f;
    for (int c = 0; c < 512; c++) acc = fmaf(f[c], w[c], acc);
    z2[n] = lrelu((acc + bl2[o]) * s7[o] + b7[o]);
}

__global__ void mlp3_kernel(const float* __restrict__ z2, const float* __restrict__ L3,
                            const float* __restrict__ bl3, float* __restrict__ out) {
    __shared__ float red[256];
    int t = threadIdx.x;
    int b = t >> 4, q = t & 15;
    float acc = 0.f;
    for (int c = q * 16; c < q * 16 + 16; c++) acc = fmaf(z2[(size_t)b * 256 + c], L3[c], acc);
    red[t] = acc;
    __syncthreads();
    if (q == 0) {
        float s = 0.f;
        #pragma unroll
        for (int i = 0; i < 16; i++) s += red[b * 16 + i];
        s += bl3[0];
        out[b] = 1.f / (1.f + expf(-s));
    }
}

extern "C" void kernel_launch(void* const* d_in, const int* in_sizes, int n_in,
                              void* d_out, int out_size, void* d_ws, size_t ws_size,
                              hipStream_t stream) {
    const float* features = (const float*)d_in[0];
    const int*   clusters = (const int*)d_in[1];
    const float* W1 = (const float*)d_in[2];
    const float* s1 = (const float*)d_in[3];
    const float* b1 = (const float*)d_in[4];
    const float* W2 = (const float*)d_in[5];
    const float* s2 = (const float*)d_in[6];
    const float* b2 = (const float*)d_in[7];
    const float* W3 = (const float*)d_in[8];
    const float* s3 = (const float*)d_in[9];
    const float* b3 = (const float*)d_in[10];
    const float* W4 = (const float*)d_in[11];
    const float* s4 = (const float*)d_in[12];
    const float* b4 = (const float*)d_in[13];
    const float* W5 = (const float*)d_in[14];
    const float* s5 = (const float*)d_in[15];
    const float* b5 = (const float*)d_in[16];
    const float* L1 = (const float*)d_in[17];
    const float* s6 = (const float*)d_in[18];
    const float* b6 = (const float*)d_in[19];
    const float* L2 = (const float*)d_in[20];
    const float* bl2 = (const float*)d_in[21];
    const float* s7 = (const float*)d_in[22];
    const float* b7 = (const float*)d_in[23];
    const float* L3 = (const float*)d_in[24];
    const float* bl3 = (const float*)d_in[25];

    float* ws = (float*)d_ws;
    // workspace layout (floats)
    constexpr size_t SZ_H0 = (size_t)NCL * PPTS * 128;      // 2,097,152
    constexpr size_t SZ_XC = (size_t)NCL * PPTS * 512;      // 8,388,608
    constexpr size_t SZ_A  = (size_t)NCL * PPTS * PPTS;     // 16,777,216 (pd, reused as U/V/y5)
    float* h0  = ws;
    float* xc  = ws + SZ_H0;
    float* regA = ws + SZ_H0 + SZ_XC;
    float* pd = regA;
    float* U  = regA;
    float* V  = regA + (size_t)NCL * PPTS * 256;
    float* y5 = regA;
    int*   idx = (int*)(ws + SZ_H0 + SZ_XC + SZ_A);
    float* sq  = ws + SZ_H0 + SZ_XC + SZ_A + (size_t)NCL * PPTS * KNN;
    float* feat = sq + (size_t)NCL * PPTS;
    float* z1 = feat + (size_t)NCL * 1024;
    float* z2 = z1 + (size_t)NCL * 512;

    gather_kernel<<<2048, 256, 0, stream>>>((const float4*)features, clusters, (float4*)h0);

    auto stage = [&](const float* hin, int ldh, int C, int O, int lgO,
                     const float* W, const float* sc, const float* bi, float* xout) {
        sq_kernel<<<4096, 256, 0, stream>>>(hin, ldh, C, sq);
        gram_kernel<<<dim3(16, 16, 16), 256, 0, stream>>>(hin, ldh, C, sq, pd);
        topk_kernel<<<dim3(256, 16), 256, 0, stream>>>(pd, idx);
        uv_kernel<<<dim3(O / 64, 256), 256, 0, stream>>>(hin, ldh, C, O, W, U, V);
        agg_kernel<<<(NCL * PPTS * O) / 256, 256, 0, stream>>>(U, V, idx, lgO, sc, bi, xout);
    };

    stage(h0,       128, 128,  64, 6, W1, s1, b1, xc + 0);
    stage(xc + 0,   512,  64,  64, 6, W2, s2, b2, xc + 64);
    stage(xc + 64,  512,  64, 128, 7, W3, s3, b3, xc + 128);
    stage(xc + 128, 512, 128, 256, 8, W4, s4, b4, xc + 256);

    conv5_kernel<<<dim3(8, 256), 256, 0, stream>>>(xc, W5, s5, b5, y5);
    pool_kernel<<<dim3(8, 16), 256, 0, stream>>>(y5, feat);
    mlp1_kernel<<<32, 256, 0, stream>>>(feat, L1, s6, b6, z1);
    mlp2_kernel<<<16, 256, 0, stream>>>(z1, L2, bl2, s7, b7, z2);
    mlp3_kernel<<<1, 256, 0, stream>>>(z2, L3, bl3, (float*)d_out);
}

// Round 2
// 904.006 us; speedup vs baseline: 1.0867x; 1.0867x over previous
//
#include <hip/hip_runtime.h>
#include <math.h>

#define KNN 20
#define PPTS 1024
#define NCL 16

typedef _Float16 f16x8 __attribute__((ext_vector_type(8)));
typedef _Float16 f16x4 __attribute__((ext_vector_type(4)));
typedef float f32x4 __attribute__((ext_vector_type(4)));

__device__ __forceinline__ float lrelu(float x) { return x > 0.f ? x : 0.2f * x; }

// ---------------- gather: h0[b*P+p, :] = features[clusters[b*P+p], :] ----------------
__global__ void gather_kernel(const float4* __restrict__ feat,
                              const int* __restrict__ clusters,
                              float4* __restrict__ h0) {
    int n = blockIdx.x * 256 + threadIdx.x;   // over NCL*PPTS*32 float4s
    int c4 = n & 31;
    int row = n >> 5;
    int src = clusters[row];
    h0[(size_t)row * 32 + c4] = feat[(size_t)src * 32 + c4];
}

// ---------------- f32 (strided) -> f16 (packed row-major) ----------------
__global__ void tof16_kernel(const float* __restrict__ src, int ldsrc, int lgC4,
                             f16x4* __restrict__ dst) {
    int n = blockIdx.x * 256 + threadIdx.x;
    int c4 = n & ((1 << lgC4) - 1);
    int row = n >> lgC4;
    float4 v = *(const float4*)&src[(size_t)row * ldsrc + c4 * 4];
    f16x4 o;
    o[0] = (_Float16)v.x; o[1] = (_Float16)v.y; o[2] = (_Float16)v.z; o[3] = (_Float16)v.w;
    dst[((size_t)row << lgC4) + c4] = o;
}

// ---------------- squared row norms (fp32 input) ----------------
__global__ void sq_kernel(const float* __restrict__ h, int ldh, int C,
                          float* __restrict__ sq) {
    int lane = threadIdx.x & 63;
    int wid  = threadIdx.x >> 6;
    int row  = blockIdx.x * 4 + wid;
    const float* hr = h + (size_t)row * ldh;
    float s = 0.f;
    for (int c = lane; c < C; c += 64) { float v = hr[c]; s += v * v; }
    #pragma unroll
    for (int off = 32; off; off >>= 1) s += __shfl_down(s, off);
    if (lane == 0) sq[row] = s;
}

// ---------------- gram via f16 MFMA: pd[b][i][j] = 2*h_i.h_j - sq_i - sq_j ----------------
// block = 4 waves; wave w computes rows i0+16w..+15 x cols j0..j0+63
__global__ __launch_bounds__(256) void gram_mfma_kernel(
    const _Float16* __restrict__ hf, int C,
    const float* __restrict__ sq, float* __restrict__ pd)
{
    const int b = blockIdx.z;
    const _Float16* hb = hf + (size_t)b * PPTS * C;
    const float* sqb = sq + b * PPTS;
    float* pdb = pd + (size_t)b * PPTS * PPTS;
    const int w = threadIdx.x >> 6;
    const int lane = threadIdx.x & 63;
    const int col16 = lane & 15, quad = lane >> 4;
    const int i0 = blockIdx.y * 64 + w * 16;
    const int j0 = blockIdx.x * 64;
    f32x4 acc[4] = {};
    for (int kk = 0; kk < C; kk += 32) {
        f16x8 a = *(const f16x8*)&hb[(size_t)(i0 + col16) * C + kk + quad * 8];
        #pragma unroll
        for (int t = 0; t < 4; t++) {
            f16x8 bf = *(const f16x8*)&hb[(size_t)(j0 + t * 16 + col16) * C + kk + quad * 8];
            acc[t] = __builtin_amdgcn_mfma_f32_16x16x32_f16(a, bf, acc[t], 0, 0, 0);
        }
    }
    float sqi[4];
    #pragma unroll
    for (int r = 0; r < 4; r++) sqi[r] = sqb[i0 + quad * 4 + r];
    #pragma unroll
    for (int t = 0; t < 4; t++) {
        int j = j0 + t * 16 + col16;
        float sqj = sqb[j];
        #pragma unroll
        for (int r = 0; r < 4; r++)
            pdb[(size_t)(i0 + quad * 4 + r) * PPTS + j] = 2.f * acc[t][r] - sqi[r] - sqj;
    }
}

// ---------------- top-K (largest pd) per row, wave per row ----------------
__global__ void topk_kernel(const float* __restrict__ pd, int* __restrict__ idx) {
    int lane = threadIdx.x & 63;
    int w = threadIdx.x >> 6;
    int b = blockIdx.y;
    int p = blockIdx.x * 4 + w;
    const float* row = pd + ((size_t)b * PPTS + p) * PPTS;
    float v[16];
    #pragma unroll
    for (int s = 0; s < 16; s++) v[s] = row[s * 64 + lane];
    int* out = idx + ((size_t)b * PPTS + p) * KNN;
    for (int kk = 0; kk < KNN; kk++) {
        float bv = v[0]; int bs = 0;
        #pragma unroll
        for (int s = 1; s < 16; s++) if (v[s] > bv) { bv = v[s]; bs = s; }
        int bj = bs * 64 + lane;
        #pragma unroll
        for (int off = 32; off; off >>= 1) {
            float ov = __shfl_down(bv, off);
            int oj = __shfl_down(bj, off);
            if (ov > bv || (ov == bv && oj < bj)) { bv = ov; bj = oj; }
        }
        bj = __shfl(bj, 0);
        if (lane == 0) out[kk] = bj;
        if ((bj & 63) == lane) v[bj >> 6] = -INFINITY;
    }
}

// ---------------- U/V GEMM (fp32): U = H*Wn^T, V = H*(Wc-Wn)^T ----------------
__global__ __launch_bounds__(256) void uv_kernel(
    const float* __restrict__ h, int ldh, int C, int O,
    const float* __restrict__ W,
    float* __restrict__ U, float* __restrict__ V)
{
    __shared__ float As[16][68];
    __shared__ float Bu[16][68];
    __shared__ float Bv[16][68];
    const int r0 = blockIdx.y * 64;
    const int o0 = blockIdx.x * 64;
    const int t = threadIdx.x;
    const int lr = t >> 2;
    const int lc = (t & 3) * 4;
    const int tx = t & 15, ty = t >> 4;
    const int twoC = 2 * C;
    float au[4][4], av[4][4];
    #pragma unroll
    for (int u = 0; u < 4; u++)
        #pragma unroll
        for (int v = 0; v < 4; v++) { au[u][v] = 0.f; av[u][v] = 0.f; }

    for (int kk = 0; kk < C; kk += 16) {
        float4 a  = *(const float4*)&h[(size_t)(r0 + lr) * ldh + kk + lc];
        float4 w1 = *(const float4*)&W[(size_t)(o0 + lr) * twoC + kk + lc];
        float4 w2 = *(const float4*)&W[(size_t)(o0 + lr) * twoC + C + kk + lc];
        __syncthreads();
        As[lc+0][lr] = a.x;  As[lc+1][lr] = a.y;  As[lc+2][lr] = a.z;  As[lc+3][lr] = a.w;
        Bu[lc+0][lr] = w1.x; Bu[lc+1][lr] = w1.y; Bu[lc+2][lr] = w1.z; Bu[lc+3][lr] = w1.w;
        Bv[lc+0][lr] = w2.x - w1.x; Bv[lc+1][lr] = w2.y - w1.y;
        Bv[lc+2][lr] = w2.z - w1.z; Bv[lc+3][lr] = w2.w - w1.w;
        __syncthreads();
        #pragma unroll
        for (int k = 0; k < 16; k++) {
            float4 ar = *(const float4*)&As[k][ty * 4];
            float4 bu = *(const float4*)&Bu[k][tx * 4];
            float4 bw = *(const float4*)&Bv[k][tx * 4];
            float arr[4] = {ar.x, ar.y, ar.z, ar.w};
            float buu[4] = {bu.x, bu.y, bu.z, bu.w};
            float bvv[4] = {bw.x, bw.y, bw.z, bw.w};
            #pragma unroll
            for (int u = 0; u < 4; u++)
                #pragma unroll
                for (int v = 0; v < 4; v++) {
                    au[u][v] = fmaf(arr[u], buu[v], au[u][v]);
                    av[u][v] = fmaf(arr[u], bvv[v], av[u][v]);
                }
        }
    }
    #pragma unroll
    for (int u = 0; u < 4; u++) {
        float4 ou = make_float4(au[u][0], au[u][1], au[u][2], au[u][3]);
        float4 ov = make_float4(av[u][0], av[u][1], av[u][2], av[u][3]);
        size_t base = (size_t)(r0 + ty * 4 + u) * O + o0 + tx * 4;
        *(float4*)&U[base] = ou;
        *(float4*)&V[base] = ov;
    }
}

// ---------------- aggregate: x[p,o] = lrelu(s*(max_k U[idx,o] + V[p,o]) + b) ----------------
__global__ void agg_kernel(const float* __restrict__ U, const float* __restrict__ V,
                           const int* __restrict__ idx, int lgO,
                           const float* __restrict__ sc, const float* __restrict__ bi,
                           float* __restrict__ xout) {
    int n = blockIdx.x * 256 + threadIdx.x;
    int O = 1 << lgO;
    int o = n & (O - 1);
    int pr = n >> lgO;           // b*P+p
    int b = pr >> 10;
    const int* id = idx + (size_t)pr * KNN;
    float m = -INFINITY;
    #pragma unroll
    for (int k = 0; k < KNN; k++) {
        int j = id[k];
        float u = U[((size_t)(b * PPTS + j) << lgO) + o];
        m = fmaxf(m, u);
    }
    float val = (m + V[((size_t)pr << lgO) + o]) * sc[o] + bi[o];
    xout[(size_t)pr * 512 + o] = lrelu(val);
}

// ---------------- conv5 via f16 MFMA: y5 = lrelu(s5*(xc @ W5^T) + b5) ----------------
__global__ __launch_bounds__(256) void conv5_mfma_kernel(
    const _Float16* __restrict__ xcf, const _Float16* __restrict__ w5f,
    const float* __restrict__ s5, const float* __restrict__ b5,
    float* __restrict__ y5)
{
    const int w = threadIdx.x >> 6;
    const int lane = threadIdx.x & 63;
    const int col16 = lane & 15, quad = lane >> 4;
    const int p0 = blockIdx.y * 64 + w * 16;
    const int o0 = blockIdx.x * 64;
    f32x4 acc[4] = {};
    for (int kk = 0; kk < 512; kk += 32) {
        f16x8 a = *(const f16x8*)&xcf[(size_t)(p0 + col16) * 512 + kk + quad * 8];
        #pragma unroll
        for (int t = 0; t < 4; t++) {
            f16x8 bf = *(const f16x8*)&w5f[(size_t)(o0 + t * 16 + col16) * 512 + kk + quad * 8];
            acc[t] = __builtin_amdgcn_mfma_f32_16x16x32_f16(a, bf, acc[t], 0, 0, 0);
        }
    }
    #pragma unroll
    for (int t = 0; t < 4; t++) {
        int o = o0 + t * 16 + col16;
        float sc = s5[o], bi = b5[o];
        #pragma unroll
        for (int r = 0; r < 4; r++) {
            int p = p0 + quad * 4 + r;
            y5[(size_t)p * 512 + o] = lrelu(acc[t][r] * sc + bi);
        }
    }
}

// ---------------- pool: feat[b] = [max_p y5, mean_p y5] ----------------
__global__ void pool_kernel(const float* __restrict__ y5, float* __restrict__ feat) {
    __shared__ float smax[256], ssum[256];
    int t = threadIdx.x;
    int ol = t & 63, st = t >> 6;
    int b = blockIdx.y;
    int o = blockIdx.x * 64 + ol;
    float m = -INFINITY, s = 0.f;
    for (int p = st; p < PPTS; p += 4) {
        float v = y5[((size_t)b * PPTS + p) * 512 + o];
        m = fmaxf(m, v); s += v;
    }
    smax[t] = m; ssum[t] = s;
    __syncthreads();
    if (st == 0) {
        #pragma unroll
        for (int q = 1; q < 4; q++) { m = fmaxf(m, smax[q * 64 + ol]); s += ssum[q * 64 + ol]; }
        feat[(size_t)b * 1024 + o] = m;
        feat[(size_t)b * 1024 + 512 + o] = s * (1.f / 1024.f);
    }
}

// ---------------- final MLP ----------------
__global__ void mlp1_kernel(const float* __restrict__ feat, const float* __restrict__ L1,
                            const float* __restrict__ s6, const float* __restrict__ b6,
                            float* __restrict__ z1) {
    int n = blockIdx.x * 256 + threadIdx.x;   // 16*512
    int o = n & 511, b = n >> 9;
    const float* f = feat + (size_t)b * 1024;
    const float* w = L1 + (size_t)o * 1024;
    float acc = 0.f;
    for (int c = 0; c < 1024; c++) acc = fmaf(f[c], w[c], acc);
    z1[n] = lrelu(acc * s6[o] + b6[o]);
}

__global__ void mlp2_kernel(const float* __restrict__ z1, const float* __restrict__ L2,
                            const float* __restrict__ bl2,
                            const float* __restrict__ s7, const float* __restrict__ b7,
                            float* __restrict__ z2) {
    int n = blockIdx.x * 256 + threadIdx.x;   // 16*256
    int o = n & 255, b = n >> 8;
    const float* f = z1 + (size_t)b * 512;
    const float* w = L2 + (size_t)o * 512;
    float acc = 0.f;
    for (int c = 0; c < 512; c++) acc = fmaf(f[c], w[c], acc);
    z2[n] = lrelu((acc + bl2[o]) * s7[o] + b7[o]);
}

__global__ void mlp3_kernel(const float* __restrict__ z2, const float* __restrict__ L3,
                            const float* __restrict__ bl3, float* __restrict__ out) {
    __shared__ float red[256];
    int t = threadIdx.x;
    int b = t >> 4, q = t & 15;
    float acc = 0.f;
    for (int c = q * 16; c < q * 16 + 16; c++) acc = fmaf(z2[(size_t)b * 256 + c], L3[c], acc);
    red[t] = acc;
    __syncthreads();
    if (q == 0) {
        float s = 0.f;
        #pragma unroll
        for (int i = 0; i < 16; i++) s += red[b * 16 + i];
        s += bl3[0];
        out[b] = 1.f / (1.f + expf(-s));
    }
}

extern "C" void kernel_launch(void* const* d_in, const int* in_sizes, int n_in,
                              void* d_out, int out_size, void* d_ws, size_t ws_size,
                              hipStream_t stream) {
    const float* features = (const float*)d_in[0];
    const int*   clusters = (const int*)d_in[1];
    const float* W1 = (const float*)d_in[2];
    const float* s1 = (const float*)d_in[3];
    const float* b1 = (const float*)d_in[4];
    const float* W2 = (const float*)d_in[5];
    const float* s2 = (const float*)d_in[6];
    const float* b2 = (const float*)d_in[7];
    const float* W3 = (const float*)d_in[8];
    const float* s3 = (const float*)d_in[9];
    const float* b3 = (const float*)d_in[10];
    const float* W4 = (const float*)d_in[11];
    const float* s4 = (const float*)d_in[12];
    const float* b4 = (const float*)d_in[13];
    const float* W5 = (const float*)d_in[14];
    const float* s5 = (const float*)d_in[15];
    const float* b5 = (const float*)d_in[16];
    const float* L1 = (const float*)d_in[17];
    const float* s6 = (const float*)d_in[18];
    const float* b6 = (const float*)d_in[19];
    const float* L2 = (const float*)d_in[20];
    const float* bl2 = (const float*)d_in[21];
    const float* s7 = (const float*)d_in[22];
    const float* b7 = (const float*)d_in[23];
    const float* L3 = (const float*)d_in[24];
    const float* bl3 = (const float*)d_in[25];

    float* ws = (float*)d_ws;
    // workspace layout (floats)
    constexpr size_t SZ_H0 = (size_t)NCL * PPTS * 128;      // 2,097,152
    constexpr size_t SZ_XC = (size_t)NCL * PPTS * 512;      // 8,388,608
    constexpr size_t SZ_A  = (size_t)NCL * PPTS * PPTS;     // 16,777,216 (pd; reused)
    float* h0  = ws;
    float* xc  = ws + SZ_H0;
    float* regA = ws + SZ_H0 + SZ_XC;
    float* pd = regA;
    float* U  = regA;
    float* V  = regA + (size_t)NCL * PPTS * 256;
    // post-stage overlay of regA:
    float* y5 = regA;                                               // 8,388,608 floats
    _Float16* xcf16 = (_Float16*)(regA + 8388608);                  // 8,388,608 halfs
    _Float16* w5f16 = (_Float16*)(regA + 8388608 + 4194304);        // 262,144 halfs
    int*   idx = (int*)(ws + SZ_H0 + SZ_XC + SZ_A);
    float* sq  = ws + SZ_H0 + SZ_XC + SZ_A + (size_t)NCL * PPTS * KNN;
    float* feat = sq + (size_t)NCL * PPTS;
    float* z1 = feat + (size_t)NCL * 1024;
    float* z2 = z1 + (size_t)NCL * 512;
    _Float16* hf16 = (_Float16*)(z2 + (size_t)NCL * 256);           // 2,097,152 halfs max

    gather_kernel<<<2048, 256, 0, stream>>>((const float4*)features, clusters, (float4*)h0);

    auto stage = [&](const float* hin, int ldh, int C, int O, int lgO,
                     const float* W, const float* sc, const float* bi, float* xout) {
        int lgC4 = (C == 128) ? 5 : 4;
        sq_kernel<<<4096, 256, 0, stream>>>(hin, ldh, C, sq);
        tof16_kernel<<<(NCL * PPTS * (C / 4)) / 256, 256, 0, stream>>>(hin, ldh, lgC4, (f16x4*)hf16);
        gram_mfma_kernel<<<dim3(16, 16, 16), 256, 0, stream>>>(hf16, C, sq, pd);
        topk_kernel<<<dim3(256, 16), 256, 0, stream>>>(pd, idx);
        uv_kernel<<<dim3(O / 64, 256), 256, 0, stream>>>(hin, ldh, C, O, W, U, V);
        agg_kernel<<<(NCL * PPTS * O) / 256, 256, 0, stream>>>(U, V, idx, lgO, sc, bi, xout);
    };

    stage(h0,       128, 128,  64, 6, W1, s1, b1, xc + 0);
    stage(xc + 0,   512,  64,  64, 6, W2, s2, b2, xc + 64);
    stage(xc + 64,  512,  64, 128, 7, W3, s3, b3, xc + 128);
    stage(xc + 128, 512, 128, 256, 8, W4, s4, b4, xc + 256);

    tof16_kernel<<<8192, 256, 0, stream>>>(xc, 512, 7, (f16x4*)xcf16);
    tof16_kernel<<<256, 256, 0, stream>>>(W5, 512, 7, (f16x4*)w5f16);
    conv5_mfma_kernel<<<dim3(8, 256), 256, 0, stream>>>(xcf16, w5f16, s5, b5, y5);
    pool_kernel<<<dim3(8, 16), 256, 0, stream>>>(y5, feat);
    mlp1_kernel<<<32, 256, 0, stream>>>(feat, L1, s6, b6, z1);
    mlp2_kernel<<<16, 256, 0, stream>>>(z1, L2, bl2, s7, b7, z2);
    mlp3_kernel<<<1, 256, 0, stream>>>(z2, L3, bl3, (float*)d_out);
}

// Round 4
// 750.610 us; speedup vs baseline: 1.3087x; 1.2044x over previous
//
#include <hip/hip_runtime.h>
#include <math.h>

#define KNN 20
#define PPTS 1024
#define NCL 16

typedef _Float16 f16x8 __attribute__((ext_vector_type(8)));
typedef _Float16 f16x4 __attribute__((ext_vector_type(4)));
typedef float f32x4 __attribute__((ext_vector_type(4)));

__device__ __forceinline__ float lrelu(float x) { return x > 0.f ? x : 0.2f * x; }

// ---------------- gather: h0 fp32 + hf16 packed ----------------
__global__ void gather_kernel(const float4* __restrict__ feat,
                              const int* __restrict__ clusters,
                              float4* __restrict__ h0,
                              f16x4* __restrict__ hf) {
    int n = blockIdx.x * 256 + threadIdx.x;   // over NCL*PPTS*32 float4s
    int c4 = n & 31;
    int row = n >> 5;
    int src = clusters[row];
    float4 v = feat[(size_t)src * 32 + c4];
    h0[(size_t)row * 32 + c4] = v;
    f16x4 o;
    o[0] = (_Float16)v.x; o[1] = (_Float16)v.y; o[2] = (_Float16)v.z; o[3] = (_Float16)v.w;
    hf[(size_t)row * 32 + c4] = o;
}

// ---------------- f32 (strided) -> f16 (packed row-major) ----------------
__global__ void tof16_kernel(const float* __restrict__ src, int ldsrc, int lgC4,
                             f16x4* __restrict__ dst) {
    int n = blockIdx.x * 256 + threadIdx.x;
    int c4 = n & ((1 << lgC4) - 1);
    int row = n >> lgC4;
    float4 v = *(const float4*)&src[(size_t)row * ldsrc + c4 * 4];
    f16x4 o;
    o[0] = (_Float16)v.x; o[1] = (_Float16)v.y; o[2] = (_Float16)v.z; o[3] = (_Float16)v.w;
    dst[((size_t)row << lgC4) + c4] = o;
}

// ---------------- weight split+convert: wn = f16(W[:, :C]), wv = f16(W[:, C:] - W[:, :C]) ----------------
__global__ void wcvt_kernel(const float* __restrict__ W, int lgC4,
                            f16x4* __restrict__ wn, f16x4* __restrict__ wv) {
    int n = blockIdx.x * 256 + threadIdx.x;   // O * C/4 threads
    int c4 = n & ((1 << lgC4) - 1);
    int o = n >> lgC4;
    int C = 4 << lgC4;
    float4 a = *(const float4*)&W[(size_t)o * 2 * C + c4 * 4];
    float4 b = *(const float4*)&W[(size_t)o * 2 * C + C + c4 * 4];
    f16x4 on, ov;
    on[0] = (_Float16)a.x; on[1] = (_Float16)a.y; on[2] = (_Float16)a.z; on[3] = (_Float16)a.w;
    ov[0] = (_Float16)(b.x - a.x); ov[1] = (_Float16)(b.y - a.y);
    ov[2] = (_Float16)(b.z - a.z); ov[3] = (_Float16)(b.w - a.w);
    wn[n] = on; wv[n] = ov;
}

// ---------------- squared row norms (fp32 input) ----------------
__global__ void sq_kernel(const float* __restrict__ h, int ldh, int C,
                          float* __restrict__ sq) {
    int lane = threadIdx.x & 63;
    int wid  = threadIdx.x >> 6;
    int row  = blockIdx.x * 4 + wid;
    const float* hr = h + (size_t)row * ldh;
    float s = 0.f;
    for (int c = lane; c < C; c += 64) { float v = hr[c]; s += v * v; }
    #pragma unroll
    for (int off = 32; off; off >>= 1) s += __shfl_down(s, off);
    if (lane == 0) sq[row] = s;
}

// ---------------- gram via f16 MFMA: pd[b][i][j] = 2*h_i.h_j - sq_i - sq_j ----------------
__global__ __launch_bounds__(256) void gram_mfma_kernel(
    const _Float16* __restrict__ hf, int C,
    const float* __restrict__ sq, float* __restrict__ pd)
{
    const int b = blockIdx.z;
    const _Float16* hb = hf + (size_t)b * PPTS * C;
    const float* sqb = sq + b * PPTS;
    float* pdb = pd + (size_t)b * PPTS * PPTS;
    const int w = threadIdx.x >> 6;
    const int lane = threadIdx.x & 63;
    const int col16 = lane & 15, quad = lane >> 4;
    const int i0 = blockIdx.y * 64 + w * 16;
    const int j0 = blockIdx.x * 64;
    f32x4 acc[4] = {};
    for (int kk = 0; kk < C; kk += 32) {
        f16x8 a = *(const f16x8*)&hb[(size_t)(i0 + col16) * C + kk + quad * 8];
        #pragma unroll
        for (int t = 0; t < 4; t++) {
            f16x8 bf = *(const f16x8*)&hb[(size_t)(j0 + t * 16 + col16) * C + kk + quad * 8];
            acc[t] = __builtin_amdgcn_mfma_f32_16x16x32_f16(a, bf, acc[t], 0, 0, 0);
        }
    }
    float sqi[4];
    #pragma unroll
    for (int r = 0; r < 4; r++) sqi[r] = sqb[i0 + quad * 4 + r];
    #pragma unroll
    for (int t = 0; t < 4; t++) {
        int j = j0 + t * 16 + col16;
        float sqj = sqb[j];
        #pragma unroll
        for (int r = 0; r < 4; r++)
            pdb[(size_t)(i0 + quad * 4 + r) * PPTS + j] = 2.f * acc[t][r] - sqi[r] - sqj;
    }
}

// ---------------- top-K via packed u32 keys: key = monotone(f32) & ~1023 | j ----------------
__global__ void topk_kernel(const float* __restrict__ pd, int* __restrict__ idx) {
    int lane = threadIdx.x & 63;
    int w = threadIdx.x >> 6;
    int b = blockIdx.y;
    int p = blockIdx.x * 4 + w;
    const float* row = pd + ((size_t)b * PPTS + p) * PPTS;
    unsigned v[16];
    #pragma unroll
    for (int s = 0; s < 16; s++) {
        int j = s * 64 + lane;
        unsigned u = __float_as_uint(row[j]);
        unsigned key = (u & 0x80000000u) ? ~u : (u | 0x80000000u);
        v[s] = (key & 0xFFFFFC00u) | (unsigned)j;
    }
    unsigned myout = 0;
    for (int kk = 0; kk < KNN; kk++) {
        unsigned m = v[0];
        #pragma unroll
        for (int s = 1; s < 16; s++) m = (v[s] > m) ? v[s] : m;
        #pragma unroll
        for (int off = 1; off < 64; off <<= 1) {
            unsigned o = (unsigned)__shfl_xor((int)m, off);
            m = (o > m) ? o : m;
        }
        unsigned j = m & 1023u;
        if (lane == kk) myout = j;
        int sj = __builtin_amdgcn_readfirstlane((int)j);
        int sslot = sj >> 6;
        bool is_lane = (lane == (sj & 63));
        #pragma unroll
        for (int s = 0; s < 16; s++)
            if (s == sslot) v[s] = is_lane ? 0u : v[s];
    }
    if (lane < KNN) idx[((size_t)b * PPTS + p) * KNN + lane] = (int)myout;
}

// ---------------- U/V via f16 MFMA: U = H*Wn^T, V = H*(Wc-Wn)^T ----------------
__global__ __launch_bounds__(256) void uv_mfma_kernel(
    const _Float16* __restrict__ hf, int C, int O,
    const _Float16* __restrict__ wn, const _Float16* __restrict__ wv,
    float* __restrict__ U, float* __restrict__ V)
{
    const int w = threadIdx.x >> 6;
    const int lane = threadIdx.x & 63;
    const int col16 = lane & 15, quad = lane >> 4;
    const int r0 = blockIdx.y * 64 + w * 16;
    const int o0 = blockIdx.x * 64;
    f32x4 au[4] = {}, av[4] = {};
    for (int kk = 0; kk < C; kk += 32) {
        f16x8 a = *(const f16x8*)&hf[(size_t)(r0 + col16) * C + kk + quad * 8];
        #pragma unroll
        for (int t = 0; t < 4; t++) {
            f16x8 bn = *(const f16x8*)&wn[(size_t)(o0 + t * 16 + col16) * C + kk + quad * 8];
            au[t] = __builtin_amdgcn_mfma_f32_16x16x32_f16(a, bn, au[t], 0, 0, 0);
            f16x8 bv = *(const f16x8*)&wv[(size_t)(o0 + t * 16 + col16) * C + kk + quad * 8];
            av[t] = __builtin_amdgcn_mfma_f32_16x16x32_f16(a, bv, av[t], 0, 0, 0);
        }
    }
    #pragma unroll
    for (int t = 0; t < 4; t++) {
        int o = o0 + t * 16 + col16;
        #pragma unroll
        for (int r = 0; r < 4; r++) {
            int p = r0 + quad * 4 + r;
            U[(size_t)p * O + o] = au[t][r];
            V[(size_t)p * O + o] = av[t][r];
        }
    }
}

// ---------------- aggregate: x = lrelu(s*(max_k U[idx] + V) + b); optional f16 hnext ----------------
__global__ void agg_kernel(const float* __restrict__ U, const float* __restrict__ V,
                           const int* __restrict__ idx, int lgO,
                           const float* __restrict__ sc, const float* __restrict__ bi,
                           float* __restrict__ xout,
                           _Float16* __restrict__ hnext) {      // packed [16K][O], may be null
    int n = blockIdx.x * 256 + threadIdx.x;
    int O = 1 << lgO;
    int o = n & (O - 1);
    int pr = n >> lgO;           // b*P+p
    int b = pr >> 10;
    const int* id = idx + (size_t)pr * KNN;
    float m = -INFINITY;
    #pragma unroll
    for (int k = 0; k < KNN; k++) {
        int j = id[k];
        float u = U[((size_t)(b * PPTS + j) << lgO) + o];
        m = fmaxf(m, u);
    }
    float val = lrelu((m + V[((size_t)pr << lgO) + o]) * sc[o] + bi[o]);
    xout[(size_t)pr * 512 + o] = val;
    if (hnext) hnext[((size_t)pr << lgO) + o] = (_Float16)val;
}

// ---------------- conv5 via f16 MFMA ----------------
__global__ __launch_bounds__(256) void conv5_mfma_kernel(
    const _Float16* __restrict__ xcf, const _Float16* __restrict__ w5f,
    const float* __restrict__ s5, const float* __restrict__ b5,
    float* __restrict__ y5)
{
    const int w = threadIdx.x >> 6;
    const int lane = threadIdx.x & 63;
    const int col16 = lane & 15, quad = lane >> 4;
    const int p0 = blockIdx.y * 64 + w * 16;
    const int o0 = blockIdx.x * 64;
    f32x4 acc[4] = {};
    for (int kk = 0; kk < 512; kk += 32) {
        f16x8 a = *(const f16x8*)&xcf[(size_t)(p0 + col16) * 512 + kk + quad * 8];
        #pragma unroll
        for (int t = 0; t < 4; t++) {
            f16x8 bf = *(const f16x8*)&w5f[(size_t)(o0 + t * 16 + col16) * 512 + kk + quad * 8];
            acc[t] = __builtin_amdgcn_mfma_f32_16x16x32_f16(a, bf, acc[t], 0, 0, 0);
        }
    }
    #pragma unroll
    for (int t = 0; t < 4; t++) {
        int o = o0 + t * 16 + col16;
        float sc = s5[o], bi = b5[o];
        #pragma unroll
        for (int r = 0; r < 4; r++) {
            int p = p0 + quad * 4 + r;
            y5[(size_t)p * 512 + o] = lrelu(acc[t][r] * sc + bi);
        }
    }
}

// ---------------- pool: feat[b] = [max_p y5, mean_p y5] ----------------
__global__ void pool_kernel(const float* __restrict__ y5, float* __restrict__ feat) {
    __shared__ float smax[256], ssum[256];
    int t = threadIdx.x;
    int ol = t & 63, st = t >> 6;
    int b = blockIdx.y;
    int o = blockIdx.x * 64 + ol;
    float m = -INFINITY, s = 0.f;
    for (int p = st; p < PPTS; p += 4) {
        float v = y5[((size_t)b * PPTS + p) * 512 + o];
        m = fmaxf(m, v); s += v;
    }
    smax[t] = m; ssum[t] = s;
    __syncthreads();
    if (st == 0) {
        #pragma unroll
        for (int q = 1; q < 4; q++) { m = fmaxf(m, smax[q * 64 + ol]); s += ssum[q * 64 + ol]; }
        feat[(size_t)b * 1024 + o] = m;
        feat[(size_t)b * 1024 + 512 + o] = s * (1.f / 1024.f);
    }
}

// ---------------- final MLP ----------------
__global__ void mlp1_kernel(const float* __restrict__ feat, const float* __restrict__ L1,
                            const float* __restrict__ s6, const float* __restrict__ b6,
                            float* __restrict__ z1) {
    int n = blockIdx.x * 256 + threadIdx.x;   // 16*512
    int o = n & 511, b = n >> 9;
    const float* f = feat + (size_t)b * 1024;
    const float* w = L1 + (size_t)o * 1024;
    float acc = 0.f;
    for (int c = 0; c < 1024; c++) acc = fmaf(f[c], w[c], acc);
    z1[n] = lrelu(acc * s6[o] + b6[o]);
}

__global__ void mlp2_kernel(const float* __restrict__ z1, const float* __restrict__ L2,
                            const float* __restrict__ bl2,
                            const float* __restrict__ s7, const float* __restrict__ b7,
                            float* __restrict__ z2) {
    int n = blockIdx.x * 256 + threadIdx.x;   // 16*256
    int o = n & 255, b = n >> 8;
    const float* f = z1 + (size_t)b * 512;
    const float* w = L2 + (size_t)o * 512;
    float acc = 0.f;
    for (int c = 0; c < 512; c++) acc = fmaf(f[c], w[c], acc);
    z2[n] = lrelu((acc + bl2[o]) * s7[o] + b7[o]);
}

__global__ void mlp3_kernel(const float* __restrict__ z2, const float* __restrict__ L3,
                            const float* __restrict__ bl3, float* __restrict__ out) {
    __shared__ float red[256];
    int t = threadIdx.x;
    int b = t >> 4, q = t & 15;
    float acc = 0.f;
    for (int c = q * 16; c < q * 16 + 16; c++) acc = fmaf(z2[(size_t)b * 256 + c], L3[c], acc);
    red[t] = acc;
    __syncthreads();
    if (q == 0) {
        float s = 0.f;
        #pragma unroll
        for (int i = 0; i < 16; i++) s += red[b * 16 + i];
        s += bl3[0];
        out[b] = 1.f / (1.f + expf(-s));
    }
}

extern "C" void kernel_launch(void* const* d_in, const int* in_sizes, int n_in,
                              void* d_out, int out_size, void* d_ws, size_t ws_size,
                              hipStream_t stream) {
    const float* features = (const float*)d_in[0];
    const int*   clusters = (const int*)d_in[1];
    const float* W1 = (const float*)d_in[2];
    const float* s1 = (const float*)d_in[3];
    const float* b1 = (const float*)d_in[4];
    const float* W2 = (const float*)d_in[5];
    const float* s2 = (const float*)d_in[6];
    const float* b2 = (const float*)d_in[7];
    const float* W3 = (const float*)d_in[8];
    const float* s3 = (const float*)d_in[9];
    const float* b3 = (const float*)d_in[10];
    const float* W4 = (const float*)d_in[11];
    const float* s4 = (const float*)d_in[12];
    const float* b4 = (const float*)d_in[13];
    const float* W5 = (const float*)d_in[14];
    const float* s5 = (const float*)d_in[15];
    const float* b5 = (const float*)d_in[16];
    const float* L1 = (const float*)d_in[17];
    const float* s6 = (const float*)d_in[18];
    const float* b6 = (const float*)d_in[19];
    const float* L2 = (const float*)d_in[20];
    const float* bl2 = (const float*)d_in[21];
    const float* s7 = (const float*)d_in[22];
    const float* b7 = (const float*)d_in[23];
    const float* L3 = (const float*)d_in[24];
    const float* bl3 = (const float*)d_in[25];

    float* ws = (float*)d_ws;
    constexpr size_t SZ_H0 = (size_t)NCL * PPTS * 128;      // 2,097,152
    constexpr size_t SZ_XC = (size_t)NCL * PPTS * 512;      // 8,388,608
    constexpr size_t SZ_A  = (size_t)NCL * PPTS * PPTS;     // 16,777,216 (pd; reused)
    float* h0  = ws;
    float* xc  = ws + SZ_H0;
    float* regA = ws + SZ_H0 + SZ_XC;
    float* pd = regA;
    float* U  = regA;
    float* V  = regA + (size_t)NCL * PPTS * 256;
    // post-stage overlay of regA (pd dead after last topk):
    float* y5 = regA;                                               // [0, 8,388,608) floats
    _Float16* xcf16 = (_Float16*)(regA + 8388608);                  // [8.4M, 12.6M) floats
    _Float16* w5f16 = (_Float16*)(regA + 8388608 + 4194304);        // [12.6M, 12.72M) floats
    int*   idx = (int*)(ws + SZ_H0 + SZ_XC + SZ_A);
    float* sq  = ws + SZ_H0 + SZ_XC + SZ_A + (size_t)NCL * PPTS * KNN;
    float* feat = sq + (size_t)NCL * PPTS;
    float* z1 = feat + (size_t)NCL * 1024;
    float* z2 = z1 + (size_t)NCL * 512;
    _Float16* hf16 = (_Float16*)(z2 + (size_t)NCL * 256);           // 2,097,152 halfs
    _Float16* wn16 = hf16 + 2097152;                                // 32,768 halfs
    _Float16* wv16 = wn16 + 32768;                                  // 32,768 halfs

    gather_kernel<<<2048, 256, 0, stream>>>((const float4*)features, clusters,
                                            (float4*)h0, (f16x4*)hf16);

    auto stage = [&](const float* hin, int ldh, int C, int O, int lgO,
                     const float* W, const float* sc, const float* bi,
                     float* xout, _Float16* hnext) {
        int lgC4 = (C == 128) ? 5 : 4;
        sq_kernel<<<4096, 256, 0, stream>>>(hin, ldh, C, sq);
        gram_mfma_kernel<<<dim3(16, 16, 16), 256, 0, stream>>>(hf16, C, sq, pd);
        topk_kernel<<<dim3(256, 16), 256, 0, stream>>>(pd, idx);
        wcvt_kernel<<<(O * (C / 4)) / 256, 256, 0, stream>>>(W, lgC4, (f16x4*)wn16, (f16x4*)wv16);
        uv_mfma_kernel<<<dim3(O / 64, 256), 256, 0, stream>>>(hf16, C, O, wn16, wv16, U, V);
        agg_kernel<<<(NCL * PPTS * O) / 256, 256, 0, stream>>>(U, V, idx, lgO, sc, bi,
                                                               xout, hnext);
    };

    stage(h0,       128, 128,  64, 6, W1, s1, b1, xc + 0,   hf16);
    stage(xc + 0,   512,  64,  64, 6, W2, s2, b2, xc + 64,  hf16);
    stage(xc + 64,  512,  64, 128, 7, W3, s3, b3, xc + 128, hf16);
    stage(xc + 128, 512, 128, 256, 8, W4, s4, b4, xc + 256, (_Float16*)nullptr);

    // pd is dead now — safe to overlay xcf16/w5f16/y5 in regA
    tof16_kernel<<<8192, 256, 0, stream>>>(xc, 512, 7, (f16x4*)xcf16);
    tof16_kernel<<<256, 256, 0, stream>>>(W5, 512, 7, (f16x4*)w5f16);
    conv5_mfma_kernel<<<dim3(8, 256), 256, 0, stream>>>(xcf16, w5f16, s5, b5, y5);
    pool_kernel<<<dim3(8, 16), 256, 0, stream>>>(y5, feat);
    mlp1_kernel<<<32, 256, 0, stream>>>(feat, L1, s6, b6, z1);
    mlp2_kernel<<<16, 256, 0, stream>>>(z1, L2, bl2, s7, b7, z2);
    mlp3_kernel<<<1, 256, 0, stream>>>(z2, L3, bl3, (float*)d_out);
}